// Round 3
// baseline (1926.616 us; speedup 1.0000x reference)
//
#include <hip/hip_runtime.h>
#include <type_traits>

#define HID 256
#define PTS 64           // points per block
#define NTHREADS 1024    // 16 waves; each wave owns a 16-wide output slice

// activation selector: m = layer % 4 : 0 sin, 1 cos, 2 gaussian, 3 tanh
template <int M>
__device__ __forceinline__ float act(float z) {
    if constexpr (M == 0) return __sinf(z);
    else if constexpr (M == 1) return __cosf(z);
    else if constexpr (M == 2) return __expf(-z * z);
    else { float e = __expf(2.0f * z); return 1.0f - 2.0f / (e + 1.0f); }
}

// VGPR budget: must stay <=64 for 8 waves/SIMD (occupancy bin steps at 64).
__global__ __launch_bounds__(NTHREADS, 8) void cppn_fused(
    const float* __restrict__ x,    // (N,12)
    const float* __restrict__ W0,   // (12,256)
    const float* __restrict__ b0,   // (256,)
    const float* __restrict__ Ws,   // (9,256,256)
    const float* __restrict__ bs,   // (9,256)
    const float* __restrict__ Wout, // (256,3)
    const float* __restrict__ bout, // (3,)
    float* __restrict__ out,        // (N,3)
    int n)
{
    __shared__ float h[HID][PTS];   // 64 KB; h[k][p]: lane-consecutive, conflict-free

    const int tid  = threadIdx.x;
    const int p    = tid & 63;                                        // lane = point
    const int j0   = __builtin_amdgcn_readfirstlane((tid >> 6) << 4); // wave's 16-out slice
    const long pg  = (long)blockIdx.x * PTS + p;                      // global point
    const bool live = (pg < n);

    // ---------------- layer 0: x(12) @ W0 + b0, sin ----------------
    {
        float xv[12];
        if (live) {
            const float4* xr = (const float4*)(x + pg * 12);
            float4 a = xr[0], b = xr[1], c = xr[2];
            xv[0]=a.x; xv[1]=a.y; xv[2]=a.z;  xv[3]=a.w;
            xv[4]=b.x; xv[5]=b.y; xv[6]=b.z;  xv[7]=b.w;
            xv[8]=c.x; xv[9]=c.y; xv[10]=c.z; xv[11]=c.w;
        } else {
            #pragma unroll
            for (int k = 0; k < 12; ++k) xv[k] = 0.0f;
        }
        float acc[16];
        #pragma unroll
        for (int q = 0; q < 16; ++q) acc[q] = 0.0f;
        #pragma unroll
        for (int k = 0; k < 12; ++k) {
            const float a = xv[k];
            const float4* wr = (const float4*)(W0 + k * HID + j0);
            #pragma unroll
            for (int q = 0; q < 4; ++q) {
                float4 w = wr[q];
                acc[4*q+0] = fmaf(a, w.x, acc[4*q+0]);
                acc[4*q+1] = fmaf(a, w.y, acc[4*q+1]);
                acc[4*q+2] = fmaf(a, w.z, acc[4*q+2]);
                acc[4*q+3] = fmaf(a, w.w, acc[4*q+3]);
            }
        }
        #pragma unroll
        for (int q = 0; q < 4; ++q) {
            float4 b4 = *(const float4*)(b0 + j0 + 4*q);
            h[j0+4*q+0][p] = act<0>(acc[4*q+0] + b4.x);
            h[j0+4*q+1][p] = act<0>(acc[4*q+1] + b4.y);
            h[j0+4*q+2][p] = act<0>(acc[4*q+2] + b4.z);
            h[j0+4*q+3][p] = act<0>(acc[4*q+3] + b4.w);
        }
        __syncthreads();
    }

    // ---------------- layers 1..9: h @ Ws[L-1] + bs[L-1] ----------------
    auto layerF = [&](const float* __restrict__ W, const float* __restrict__ b,
                      auto mtag) {
        constexpr int M = decltype(mtag)::value;
        float acc[16];
        #pragma unroll
        for (int q = 0; q < 16; ++q) acc[q] = 0.0f;
        #pragma unroll 4
        for (int k = 0; k < HID; ++k) {
            const float a = h[k][p];
            const float4* wr = (const float4*)(W + k * HID + j0);
            #pragma unroll
            for (int q = 0; q < 4; ++q) {
                float4 w = wr[q];
                acc[4*q+0] = fmaf(a, w.x, acc[4*q+0]);
                acc[4*q+1] = fmaf(a, w.y, acc[4*q+1]);
                acc[4*q+2] = fmaf(a, w.z, acc[4*q+2]);
                acc[4*q+3] = fmaf(a, w.w, acc[4*q+3]);
            }
        }
        __syncthreads();   // all reads of h done before overwrite
        #pragma unroll
        for (int q = 0; q < 4; ++q) {
            float4 b4 = *(const float4*)(b + j0 + 4*q);
            h[j0+4*q+0][p] = act<M>(acc[4*q+0] + b4.x);
            h[j0+4*q+1][p] = act<M>(acc[4*q+1] + b4.y);
            h[j0+4*q+2][p] = act<M>(acc[4*q+2] + b4.z);
            h[j0+4*q+3][p] = act<M>(acc[4*q+3] + b4.w);
        }
        __syncthreads();
    };

    layerF(Ws + 0*65536, bs + 0*256, std::integral_constant<int,1>{});
    layerF(Ws + 1*65536, bs + 1*256, std::integral_constant<int,2>{});
    layerF(Ws + 2*65536, bs + 2*256, std::integral_constant<int,3>{});
    layerF(Ws + 3*65536, bs + 3*256, std::integral_constant<int,0>{});
    layerF(Ws + 4*65536, bs + 4*256, std::integral_constant<int,1>{});
    layerF(Ws + 5*65536, bs + 5*256, std::integral_constant<int,2>{});
    layerF(Ws + 6*65536, bs + 6*256, std::integral_constant<int,3>{});
    layerF(Ws + 7*65536, bs + 7*256, std::integral_constant<int,0>{});
    layerF(Ws + 8*65536, bs + 8*256, std::integral_constant<int,1>{});

    // ---------------- output: h @ Wout + bout, sigmoid ----------------
    if (tid < 192) {
        const int pp = tid & 63;
        const int c  = tid >> 6;            // 0..2
        const long pgo = (long)blockIdx.x * PTS + pp;
        if (pgo < n) {
            float z = bout[c];
            #pragma unroll 4
            for (int k = 0; k < HID; ++k)
                z = fmaf(h[k][pp], Wout[k * 3 + c], z);
            out[pgo * 3 + c] = 1.0f / (1.0f + __expf(-z));
        }
    }
}

extern "C" void kernel_launch(void* const* d_in, const int* in_sizes, int n_in,
                              void* d_out, int out_size, void* d_ws, size_t ws_size,
                              hipStream_t stream) {
    const float* x    = (const float*)d_in[0];
    const float* W0   = (const float*)d_in[1];
    const float* b0   = (const float*)d_in[2];
    const float* Ws   = (const float*)d_in[3];
    const float* bs   = (const float*)d_in[4];
    const float* Wout = (const float*)d_in[5];
    const float* bout = (const float*)d_in[6];
    float* out = (float*)d_out;

    const int n = in_sizes[0] / 12;          // number of points
    const int grid = (n + PTS - 1) / PTS;    // 2048 for N=131072

    cppn_fused<<<grid, NTHREADS, 0, stream>>>(x, W0, b0, Ws, bs, Wout, bout, out, n);
}

// Round 5
// 1224.809 us; speedup vs baseline: 1.5730x; 1.5730x over previous
//
#include <hip/hip_runtime.h>
#include <type_traits>

#define HID 256
#define PTS 64
typedef unsigned short ushort_t;
typedef unsigned int uint_t;
typedef __attribute__((ext_vector_type(8))) _Float16 half8v;  // 8 fp16 = 4 VGPR
typedef __attribute__((ext_vector_type(4))) float f32x4;

#define LO_SCALE   4096.0f          // 2^12
#define LO_INV     0.000244140625f  // 2^-12

__device__ __forceinline__ ushort_t h_bits(_Float16 h) { return __builtin_bit_cast(ushort_t, h); }

// activation: m = layer % 4 : 0 sin, 1 cos, 2 gaussian, 3 tanh
template <int M>
__device__ __forceinline__ float act(float z) {
    if constexpr (M == 0) return __sinf(z);
    else if constexpr (M == 1) return __cosf(z);
    else if constexpr (M == 2) return __expf(-z * z);
    else { float e = __expf(2.0f * z); return 1.0f - 2.0f / (e + 1.0f); }
}

// =====================================================================
// Weight prep: split Ws (9,256,256) fp32 into fp16 hi + scaled fp16 lo
// (lo' = (w - hi)*4096), pre-swizzled into MFMA B-fragment order.
// frag f = ((L*8+kt)*16+ct); lane l, elem j -> W[L][kt*32+(l>>4)*8+j][ct*16+(l&15)]
// stored at (f*64 + l)*8 + j (lane-contiguous 16B).
// =====================================================================
#define NFRAG (9 * 8 * 16)          // 1152 frags
#define PREP_THREADS (NFRAG * 64)   // 73728

__global__ void prep_w(const float* __restrict__ Ws,
                       _Float16* __restrict__ WHI, _Float16* __restrict__ WLO) {
    int t = blockIdx.x * 256 + threadIdx.x;
    if (t >= PREP_THREADS) return;
    int l  = t & 63;
    int f  = t >> 6;            // 0..1151
    int ct = f & 15;
    int kt = (f >> 4) & 7;
    int L  = f >> 7;            // 0..8
    int col = ct * 16 + (l & 15);
    int kb  = kt * 32 + (l >> 4) * 8;
    const float* Wp = Ws + (size_t)L * 65536;
    _Float16* oh = WHI + (size_t)t * 8;
    _Float16* ol = WLO + (size_t)t * 8;
    #pragma unroll
    for (int j = 0; j < 8; ++j) {
        float wv = Wp[(size_t)(kb + j) * 256 + col];
        _Float16 hi = (_Float16)wv;                       // RNE
        oh[j] = hi;
        ol[j] = (_Float16)((wv - (float)hi) * LO_SCALE);  // scaled lo, always normal
    }
}

// =====================================================================
// Main fused kernel: 512 threads = 8 waves, 64 points/block.
// LDS h as [p][k] fp16 hi / scaled-lo, XOR-swizzle elem = p*256 + (k ^ ((p&7)<<3)).
// Wave w: row-tile rt=w&3 (16 points), col-half ch=w>>2 (8 col-tiles of 16).
// Split-fp16 MFMA: acc  += Ahi*Bhi
//                  accL += Ahi*Blo' + Alo'*Bhi     (both at 2^12 scale)
// z = acc + accL*2^-12  -> effective precision ~2^-24.
// =====================================================================
__global__ __launch_bounds__(512, 4) void cppn_mfma(
    const float* __restrict__ x,    // (N,12)
    const float* __restrict__ W0,   // (12,256)
    const float* __restrict__ b0,   // (256,)
    const float* __restrict__ bs,   // (9,256)
    const float* __restrict__ Wout, // (256,3)
    const float* __restrict__ bout, // (3,)
    const _Float16* __restrict__ WHI,
    const _Float16* __restrict__ WLO,
    float* __restrict__ out,        // (N,3)
    int n)
{
    __shared__ ushort_t ha[64 * 256];   // 32 KB hi
    __shared__ ushort_t hb[64 * 256];   // 32 KB lo (scaled)

    const int tid = threadIdx.x;
    const int l   = tid & 63;
    const int w   = tid >> 6;           // wave 0..7
    const long p0 = (long)blockIdx.x * PTS;

    // ---------------- layer 0 (fp32): point p=l, cols [w*32, w*32+32) ----
    {
        const int p  = l;
        const long pg = p0 + p;
        float xv[12];
        if (pg < n) {
            const float4* xr = (const float4*)(x + pg * 12);
            float4 a = xr[0], b = xr[1], c = xr[2];
            xv[0]=a.x; xv[1]=a.y; xv[2]=a.z;  xv[3]=a.w;
            xv[4]=b.x; xv[5]=b.y; xv[6]=b.z;  xv[7]=b.w;
            xv[8]=c.x; xv[9]=c.y; xv[10]=c.z; xv[11]=c.w;
        } else {
            #pragma unroll
            for (int k = 0; k < 12; ++k) xv[k] = 0.0f;
        }
        const int jb = w * 32;
        float z[32];
        #pragma unroll
        for (int jj = 0; jj < 32; ++jj) z[jj] = b0[jb + jj];
        #pragma unroll
        for (int k = 0; k < 12; ++k) {
            const float a = xv[k];
            #pragma unroll
            for (int jj = 0; jj < 32; ++jj)
                z[jj] = fmaf(a, W0[k * HID + jb + jj], z[jj]);
        }
        const int swz = (p & 7) << 3;
        #pragma unroll
        for (int jj = 0; jj < 32; jj += 2) {
            float v0 = act<0>(z[jj]), v1 = act<0>(z[jj + 1]);
            _Float16 h0 = (_Float16)v0, h1 = (_Float16)v1;
            _Float16 l0 = (_Float16)((v0 - (float)h0) * LO_SCALE);
            _Float16 l1 = (_Float16)((v1 - (float)h1) * LO_SCALE);
            int ei = p * 256 + ((jb + jj) ^ swz);          // even -> 4B aligned
            *(uint_t*)&ha[ei] = (uint_t)h_bits(h0) | ((uint_t)h_bits(h1) << 16);
            *(uint_t*)&hb[ei] = (uint_t)h_bits(l0) | ((uint_t)h_bits(l1) << 16);
        }
    }
    __syncthreads();

    // ---------------- layers 1..9: split-fp16 MFMA --------------------
    const int rt   = w & 3;             // row-tile (points rt*16..rt*16+15)
    const int ch   = w >> 2;            // col half (col-tiles ch*8..ch*8+7)
    const int lg   = l >> 4;            // k-group 0..3
    const int arow = rt * 16 + (l & 15);
    const int albase = arow * 256;
    const int aswz = (l & 7) << 3;      // (arow&7)<<3 == (l&7)<<3

    for (int Li = 0; Li < 9; ++Li) {
        f32x4 acc[8], accL[8];
        #pragma unroll
        for (int t = 0; t < 8; ++t) {
            acc[t]  = (f32x4){0.f, 0.f, 0.f, 0.f};
            accL[t] = (f32x4){0.f, 0.f, 0.f, 0.f};
        }

        for (int kt = 0; kt < 8; ++kt) {
            const int kb = kt * 32 + lg * 8;
            const int ae = albase + (kb ^ aswz);
            half8v ahi = *(const half8v*)&ha[ae];
            half8v alo = *(const half8v*)&hb[ae];
            const size_t fb = ((size_t)((Li * 8 + kt) * 16 + ch * 8)) * 512 + (size_t)l * 8;
            const _Float16* wh = WHI + fb;
            const _Float16* wl = WLO + fb;
            #pragma unroll
            for (int t = 0; t < 8; ++t) {
                half8v bhi = *(const half8v*)(wh + t * 512);
                half8v blo = *(const half8v*)(wl + t * 512);
                acc[t]  = __builtin_amdgcn_mfma_f32_16x16x32_f16(ahi, bhi, acc[t],  0, 0, 0);
                accL[t] = __builtin_amdgcn_mfma_f32_16x16x32_f16(ahi, blo, accL[t], 0, 0, 0);
                accL[t] = __builtin_amdgcn_mfma_f32_16x16x32_f16(alo, bhi, accL[t], 0, 0, 0);
            }
        }
        __syncthreads();   // all LDS reads of this layer done

        const float* bsL = bs + Li * 256;
        const int m = (Li + 1) & 3;
        auto storeact = [&](auto mt) {
            constexpr int M = decltype(mt)::value;
            #pragma unroll
            for (int t = 0; t < 8; ++t) {
                const int j  = ch * 128 + t * 16 + (l & 15);
                const float bj = bsL[j];
                #pragma unroll
                for (int r = 0; r < 4; ++r) {
                    const int p = rt * 16 + lg * 4 + r;
                    float zv = acc[t][r] + accL[t][r] * LO_INV + bj;
                    float v = act<M>(zv);
                    _Float16 vh = (_Float16)v;
                    _Float16 vl = (_Float16)((v - (float)vh) * LO_SCALE);
                    const int ei = p * 256 + (j ^ ((p & 7) << 3));
                    ha[ei] = h_bits(vh);
                    hb[ei] = h_bits(vl);
                }
            }
        };
        if      (m == 0) storeact(std::integral_constant<int,0>{});
        else if (m == 1) storeact(std::integral_constant<int,1>{});
        else if (m == 2) storeact(std::integral_constant<int,2>{});
        else             storeact(std::integral_constant<int,3>{});
        __syncthreads();
    }

    // ---------------- output: h @ Wout + bout, sigmoid ------------------
    if (tid < 192) {
        const int p = tid & 63;
        const int c = tid >> 6;             // 0..2 (wave-uniform)
        const long pg = p0 + p;
        if (pg < n) {
            const int swz = (p & 7) << 3;
            float zacc = bout[c];
            #pragma unroll 4
            for (int c2 = 0; c2 < 32; ++c2) {
                const int ei = p * 256 + ((c2 * 8) ^ swz);
                half8v vh = *(const half8v*)&ha[ei];
                half8v vl = *(const half8v*)&hb[ei];
                #pragma unroll
                for (int e = 0; e < 8; ++e) {
                    const int k = c2 * 8 + e;
                    float hv = (float)vh[e] + (float)vl[e] * LO_INV;
                    zacc = fmaf(hv, Wout[k * 3 + c], zacc);
                }
            }
            out[pg * 3 + c] = 1.0f / (1.0f + __expf(-zacc));
        }
    }
}

// =====================================================================
// Fallback (fp32, R2 structure) if ws too small for the split weights.
// =====================================================================
__global__ __launch_bounds__(512, 4) void cppn_fused_fp32(
    const float* __restrict__ x, const float* __restrict__ W0,
    const float* __restrict__ b0, const float* __restrict__ Ws,
    const float* __restrict__ bs, const float* __restrict__ Wout,
    const float* __restrict__ bout, float* __restrict__ out, int n)
{
    __shared__ float h[HID][PTS];
    const int tid  = threadIdx.x;
    const int p    = tid & 63;
    const int j0   = __builtin_amdgcn_readfirstlane((tid >> 6) << 5);
    const long pg  = (long)blockIdx.x * PTS + p;
    const bool live = (pg < n);
    {
        float xv[12];
        if (live) {
            const float4* xr = (const float4*)(x + pg * 12);
            float4 a = xr[0], b = xr[1], c = xr[2];
            xv[0]=a.x; xv[1]=a.y; xv[2]=a.z;  xv[3]=a.w;
            xv[4]=b.x; xv[5]=b.y; xv[6]=b.z;  xv[7]=b.w;
            xv[8]=c.x; xv[9]=c.y; xv[10]=c.z; xv[11]=c.w;
        } else {
            #pragma unroll
            for (int k = 0; k < 12; ++k) xv[k] = 0.0f;
        }
        float acc[32];
        #pragma unroll
        for (int q = 0; q < 32; ++q) acc[q] = 0.0f;
        #pragma unroll
        for (int k = 0; k < 12; ++k) {
            const float a = xv[k];
            const float4* wr = (const float4*)(W0 + k * HID + j0);
            #pragma unroll
            for (int q = 0; q < 8; ++q) {
                float4 wv = wr[q];
                acc[4*q+0] = fmaf(a, wv.x, acc[4*q+0]);
                acc[4*q+1] = fmaf(a, wv.y, acc[4*q+1]);
                acc[4*q+2] = fmaf(a, wv.z, acc[4*q+2]);
                acc[4*q+3] = fmaf(a, wv.w, acc[4*q+3]);
            }
        }
        #pragma unroll
        for (int q = 0; q < 8; ++q) {
            float4 b4 = *(const float4*)(b0 + j0 + 4*q);
            h[j0+4*q+0][p] = act<0>(acc[4*q+0] + b4.x);
            h[j0+4*q+1][p] = act<0>(acc[4*q+1] + b4.y);
            h[j0+4*q+2][p] = act<0>(acc[4*q+2] + b4.z);
            h[j0+4*q+3][p] = act<0>(acc[4*q+3] + b4.w);
        }
        __syncthreads();
    }
    auto layerF = [&](const float* __restrict__ W, const float* __restrict__ b, auto mtag) {
        constexpr int M = decltype(mtag)::value;
        float acc[32];
        #pragma unroll
        for (int q = 0; q < 32; ++q) acc[q] = 0.0f;
        #pragma unroll 2
        for (int k = 0; k < HID; ++k) {
            const float a = h[k][p];
            const float4* wr = (const float4*)(W + k * HID + j0);
            #pragma unroll
            for (int q = 0; q < 8; ++q) {
                float4 wv = wr[q];
                acc[4*q+0] = fmaf(a, wv.x, acc[4*q+0]);
                acc[4*q+1] = fmaf(a, wv.y, acc[4*q+1]);
                acc[4*q+2] = fmaf(a, wv.z, acc[4*q+2]);
                acc[4*q+3] = fmaf(a, wv.w, acc[4*q+3]);
            }
        }
        __syncthreads();
        #pragma unroll
        for (int q = 0; q < 8; ++q) {
            float4 b4 = *(const float4*)(b + j0 + 4*q);
            h[j0+4*q+0][p] = act<M>(acc[4*q+0] + b4.x);
            h[j0+4*q+1][p] = act<M>(acc[4*q+1] + b4.y);
            h[j0+4*q+2][p] = act<M>(acc[4*q+2] + b4.z);
            h[j0+4*q+3][p] = act<M>(acc[4*q+3] + b4.w);
        }
        __syncthreads();
    };
    layerF(Ws + 0*65536, bs + 0*256, std::integral_constant<int,1>{});
    layerF(Ws + 1*65536, bs + 1*256, std::integral_constant<int,2>{});
    layerF(Ws + 2*65536, bs + 2*256, std::integral_constant<int,3>{});
    layerF(Ws + 3*65536, bs + 3*256, std::integral_constant<int,0>{});
    layerF(Ws + 4*65536, bs + 4*256, std::integral_constant<int,1>{});
    layerF(Ws + 5*65536, bs + 5*256, std::integral_constant<int,2>{});
    layerF(Ws + 6*65536, bs + 6*256, std::integral_constant<int,3>{});
    layerF(Ws + 7*65536, bs + 7*256, std::integral_constant<int,0>{});
    layerF(Ws + 8*65536, bs + 8*256, std::integral_constant<int,1>{});
    if (tid < 192) {
        const int pp = tid & 63;
        const int c  = tid >> 6;
        const long pgo = (long)blockIdx.x * PTS + pp;
        if (pgo < n) {
            float z = bout[c];
            #pragma unroll 4
            for (int k = 0; k < HID; ++k)
                z = fmaf(h[k][pp], Wout[k * 3 + c], z);
            out[pgo * 3 + c] = 1.0f / (1.0f + __expf(-z));
        }
    }
}

extern "C" void kernel_launch(void* const* d_in, const int* in_sizes, int n_in,
                              void* d_out, int out_size, void* d_ws, size_t ws_size,
                              hipStream_t stream) {
    const float* x    = (const float*)d_in[0];
    const float* W0   = (const float*)d_in[1];
    const float* b0   = (const float*)d_in[2];
    const float* Ws   = (const float*)d_in[3];
    const float* bs   = (const float*)d_in[4];
    const float* Wout = (const float*)d_in[5];
    const float* bout = (const float*)d_in[6];
    float* out = (float*)d_out;

    const int n = in_sizes[0] / 12;
    const int grid = (n + PTS - 1) / PTS;

    const size_t whi_bytes = (size_t)PREP_THREADS * 8 * sizeof(_Float16); // 1,179,648
    const size_t need = 2 * whi_bytes;

    if (ws_size >= need) {
        _Float16* WHI = (_Float16*)d_ws;
        _Float16* WLO = (_Float16*)((char*)d_ws + whi_bytes);
        prep_w<<<(PREP_THREADS + 255) / 256, 256, 0, stream>>>(Ws, WHI, WLO);
        cppn_mfma<<<grid, 512, 0, stream>>>(x, W0, b0, bs, Wout, bout, WHI, WLO, out, n);
    } else {
        cppn_fused_fp32<<<grid, 512, 0, stream>>>(x, W0, b0, Ws, bs, Wout, bout, out, n);
    }
}

// Round 6
// 469.891 us; speedup vs baseline: 4.1001x; 2.6066x over previous
//
#include <hip/hip_runtime.h>
#include <type_traits>

#define HID 256
#define PTS 64
typedef unsigned short ushort_t;
typedef unsigned int uint_t;
typedef __attribute__((ext_vector_type(8))) _Float16 half8v;  // 8 fp16 = 4 VGPR
typedef __attribute__((ext_vector_type(4))) float f32x4;

#define LO_SCALE   4096.0f          // 2^12
#define LO_INV     0.000244140625f  // 2^-12

__device__ __forceinline__ ushort_t h_bits(_Float16 h) { return __builtin_bit_cast(ushort_t, h); }

// activation: m = layer % 4 : 0 sin, 1 cos, 2 gaussian, 3 tanh
template <int M>
__device__ __forceinline__ float act(float z) {
    if constexpr (M == 0) return __sinf(z);
    else if constexpr (M == 1) return __cosf(z);
    else if constexpr (M == 2) return __expf(-z * z);
    else { float e = __expf(2.0f * z); return 1.0f - 2.0f / (e + 1.0f); }
}

// =====================================================================
// Weight prep: split Ws (9,256,256) fp32 into fp16 hi + scaled fp16 lo
// (lo' = (w - hi)*4096), pre-swizzled into MFMA B-fragment order.
// frag f = ((L*8+kt)*16+ct); lane l, elem j -> W[L][kt*32+(l>>4)*8+j][ct*16+(l&15)]
// stored at (f*64 + l)*8 + j (lane-contiguous 16B).
// =====================================================================
#define NFRAG (9 * 8 * 16)          // 1152 frags
#define PREP_THREADS (NFRAG * 64)   // 73728

__global__ void prep_w(const float* __restrict__ Ws,
                       _Float16* __restrict__ WHI, _Float16* __restrict__ WLO) {
    int t = blockIdx.x * 256 + threadIdx.x;
    if (t >= PREP_THREADS) return;
    int l  = t & 63;
    int f  = t >> 6;            // 0..1151
    int ct = f & 15;
    int kt = (f >> 4) & 7;
    int L  = f >> 7;            // 0..8
    int col = ct * 16 + (l & 15);
    int kb  = kt * 32 + (l >> 4) * 8;
    const float* Wp = Ws + (size_t)L * 65536;
    _Float16* oh = WHI + (size_t)t * 8;
    _Float16* ol = WLO + (size_t)t * 8;
    #pragma unroll
    for (int j = 0; j < 8; ++j) {
        float wv = Wp[(size_t)(kb + j) * 256 + col];
        _Float16 hi = (_Float16)wv;                       // RNE
        oh[j] = hi;
        ol[j] = (_Float16)((wv - (float)hi) * LO_SCALE);  // scaled lo, always normal
    }
}

// =====================================================================
// Main fused kernel: 512 threads = 8 waves, 64 points/block.
// LDS h as [p][k] fp16 hi / scaled-lo, XOR-swizzle elem = p*256 + (k ^ ((p&7)<<3)).
// Wave w: ALL 64 rows x 32-col slice (ct pair w*2, w*2+1) -> each W frag
// loaded exactly once per block (4x fewer global loads than R5).
// B-frags register-double-buffered (prefetch kt+1 during kt's MFMAs).
// Split-fp16 MFMA: acc += Ahi*Bhi ; accL += Ahi*Blo' + Alo'*Bhi (2^12 scale)
// z = acc + accL*2^-12.
// =====================================================================
__global__ __launch_bounds__(512, 4) void cppn_mfma(
    const float* __restrict__ x,    // (N,12)
    const float* __restrict__ W0,   // (12,256)
    const float* __restrict__ b0,   // (256,)
    const float* __restrict__ bs,   // (9,256)
    const float* __restrict__ Wout, // (256,3)
    const float* __restrict__ bout, // (3,)
    const _Float16* __restrict__ WHI,
    const _Float16* __restrict__ WLO,
    float* __restrict__ out,        // (N,3)
    int n)
{
    __shared__ ushort_t ha[64 * 256];   // 32 KB hi
    __shared__ ushort_t hb[64 * 256];   // 32 KB lo (scaled)

    const int tid = threadIdx.x;
    const int l   = tid & 63;
    const int w   = tid >> 6;           // wave 0..7
    const long p0 = (long)blockIdx.x * PTS;

    // ---------------- layer 0 (fp32): point p=l, cols [w*32, w*32+32) ----
    {
        const int p  = l;
        const long pg = p0 + p;
        float xv[12];
        if (pg < n) {
            const float4* xr = (const float4*)(x + pg * 12);
            float4 a = xr[0], b = xr[1], c = xr[2];
            xv[0]=a.x; xv[1]=a.y; xv[2]=a.z;  xv[3]=a.w;
            xv[4]=b.x; xv[5]=b.y; xv[6]=b.z;  xv[7]=b.w;
            xv[8]=c.x; xv[9]=c.y; xv[10]=c.z; xv[11]=c.w;
        } else {
            #pragma unroll
            for (int k = 0; k < 12; ++k) xv[k] = 0.0f;
        }
        const int jb = w * 32;
        float z[32];
        #pragma unroll
        for (int jj = 0; jj < 32; ++jj) z[jj] = b0[jb + jj];
        #pragma unroll
        for (int k = 0; k < 12; ++k) {
            const float a = xv[k];
            #pragma unroll
            for (int jj = 0; jj < 32; ++jj)
                z[jj] = fmaf(a, W0[k * HID + jb + jj], z[jj]);
        }
        const int swz = (p & 7) << 3;
        #pragma unroll
        for (int jj = 0; jj < 32; jj += 2) {
            float v0 = act<0>(z[jj]), v1 = act<0>(z[jj + 1]);
            _Float16 h0 = (_Float16)v0, h1 = (_Float16)v1;
            _Float16 l0 = (_Float16)((v0 - (float)h0) * LO_SCALE);
            _Float16 l1 = (_Float16)((v1 - (float)h1) * LO_SCALE);
            int ei = p * 256 + ((jb + jj) ^ swz);          // even -> 4B aligned
            *(uint_t*)&ha[ei] = (uint_t)h_bits(h0) | ((uint_t)h_bits(h1) << 16);
            *(uint_t*)&hb[ei] = (uint_t)h_bits(l0) | ((uint_t)h_bits(l1) << 16);
        }
    }
    __syncthreads();

    // ---------------- layers 1..9: split-fp16 MFMA --------------------
    const int lg   = l >> 4;            // k-group 0..3
    const int lm   = l & 15;
    const int aswz = (l & 7) << 3;      // (row&7)<<3 == (l&7)<<3 for all rt
    const int ab[4] = { (0*16+lm)*256, (1*16+lm)*256, (2*16+lm)*256, (3*16+lm)*256 };

    for (int Li = 0; Li < 9; ++Li) {
        const _Float16* __restrict__ WHL = WHI + (size_t)(Li * 8 * 16) * 512 + (size_t)l * 8;
        const _Float16* __restrict__ WLL = WLO + (size_t)(Li * 8 * 16) * 512 + (size_t)l * 8;

        f32x4 acc[4][2], accL[4][2];
        #pragma unroll
        for (int rt = 0; rt < 4; ++rt)
            #pragma unroll
            for (int c = 0; c < 2; ++c) {
                acc[rt][c]  = (f32x4){0.f, 0.f, 0.f, 0.f};
                accL[rt][c] = (f32x4){0.f, 0.f, 0.f, 0.f};
            }

        // B fragment offset for (kt, c): (kt*16 + w*2 + c)*512 (lane term folded in)
        half8v bch[2], bcl[2];
        bch[0] = *(const half8v*)(WHL + (size_t)(w * 2 + 0) * 512);
        bch[1] = *(const half8v*)(WHL + (size_t)(w * 2 + 1) * 512);
        bcl[0] = *(const half8v*)(WLL + (size_t)(w * 2 + 0) * 512);
        bcl[1] = *(const half8v*)(WLL + (size_t)(w * 2 + 1) * 512);

        #pragma unroll 1
        for (int kt = 0; kt < 8; ++kt) {
            // prefetch next kt's B frags (kt=7 redundantly reloads kt=0: harmless)
            const int ktn = (kt + 1) & 7;
            half8v bnh[2], bnl[2];
            bnh[0] = *(const half8v*)(WHL + (size_t)(ktn * 16 + w * 2 + 0) * 512);
            bnh[1] = *(const half8v*)(WHL + (size_t)(ktn * 16 + w * 2 + 1) * 512);
            bnl[0] = *(const half8v*)(WLL + (size_t)(ktn * 16 + w * 2 + 0) * 512);
            bnl[1] = *(const half8v*)(WLL + (size_t)(ktn * 16 + w * 2 + 1) * 512);

            const int ke = (kt * 32 + lg * 8) ^ aswz;

            // ---- rt half 0 (rt 0,1) ----
            {
                half8v a_hi[2], a_lo[2];
                a_hi[0] = *(const half8v*)&ha[ab[0] + ke];
                a_hi[1] = *(const half8v*)&ha[ab[1] + ke];
                a_lo[0] = *(const half8v*)&hb[ab[0] + ke];
                a_lo[1] = *(const half8v*)&hb[ab[1] + ke];
                #pragma unroll
                for (int c = 0; c < 2; ++c)
                    #pragma unroll
                    for (int r = 0; r < 2; ++r)
                        acc[r][c] = __builtin_amdgcn_mfma_f32_16x16x32_f16(a_hi[r], bch[c], acc[r][c], 0, 0, 0);
                #pragma unroll
                for (int c = 0; c < 2; ++c)
                    #pragma unroll
                    for (int r = 0; r < 2; ++r)
                        accL[r][c] = __builtin_amdgcn_mfma_f32_16x16x32_f16(a_hi[r], bcl[c], accL[r][c], 0, 0, 0);
                #pragma unroll
                for (int c = 0; c < 2; ++c)
                    #pragma unroll
                    for (int r = 0; r < 2; ++r)
                        accL[r][c] = __builtin_amdgcn_mfma_f32_16x16x32_f16(a_lo[r], bch[c], accL[r][c], 0, 0, 0);
            }
            // ---- rt half 1 (rt 2,3) ----
            {
                half8v a_hi[2], a_lo[2];
                a_hi[0] = *(const half8v*)&ha[ab[2] + ke];
                a_hi[1] = *(const half8v*)&ha[ab[3] + ke];
                a_lo[0] = *(const half8v*)&hb[ab[2] + ke];
                a_lo[1] = *(const half8v*)&hb[ab[3] + ke];
                #pragma unroll
                for (int c = 0; c < 2; ++c)
                    #pragma unroll
                    for (int r = 0; r < 2; ++r)
                        acc[2+r][c] = __builtin_amdgcn_mfma_f32_16x16x32_f16(a_hi[r], bch[c], acc[2+r][c], 0, 0, 0);
                #pragma unroll
                for (int c = 0; c < 2; ++c)
                    #pragma unroll
                    for (int r = 0; r < 2; ++r)
                        accL[2+r][c] = __builtin_amdgcn_mfma_f32_16x16x32_f16(a_hi[r], bcl[c], accL[2+r][c], 0, 0, 0);
                #pragma unroll
                for (int c = 0; c < 2; ++c)
                    #pragma unroll
                    for (int r = 0; r < 2; ++r)
                        accL[2+r][c] = __builtin_amdgcn_mfma_f32_16x16x32_f16(a_lo[r], bch[c], accL[2+r][c], 0, 0, 0);
            }
            bch[0] = bnh[0]; bch[1] = bnh[1];
            bcl[0] = bnl[0]; bcl[1] = bnl[1];
        }
        __syncthreads();   // all LDS reads of this layer done

        const float* bsL = bs + Li * 256;
        const int m = (Li + 1) & 3;
        auto storeact = [&](auto mt) {
            constexpr int M = decltype(mt)::value;
            #pragma unroll
            for (int c = 0; c < 2; ++c) {
                const int j  = w * 32 + c * 16 + lm;
                const float bj = bsL[j];
                #pragma unroll
                for (int rt = 0; rt < 4; ++rt) {
                    #pragma unroll
                    for (int r = 0; r < 4; ++r) {
                        const int p = rt * 16 + lg * 4 + r;
                        float zv = acc[rt][c][r] + accL[rt][c][r] * LO_INV + bj;
                        float v = act<M>(zv);
                        _Float16 vh = (_Float16)v;
                        _Float16 vl = (_Float16)((v - (float)vh) * LO_SCALE);
                        const int ei = p * 256 + (j ^ ((p & 7) << 3));
                        ha[ei] = h_bits(vh);
                        hb[ei] = h_bits(vl);
                    }
                }
            }
        };
        if      (m == 0) storeact(std::integral_constant<int,0>{});
        else if (m == 1) storeact(std::integral_constant<int,1>{});
        else if (m == 2) storeact(std::integral_constant<int,2>{});
        else             storeact(std::integral_constant<int,3>{});
        __syncthreads();
    }

    // ---------------- output: h @ Wout + bout, sigmoid ------------------
    if (tid < 192) {
        const int p = tid & 63;
        const int c = tid >> 6;             // 0..2 (wave-uniform)
        const long pg = p0 + p;
        if (pg < n) {
            const int swz = (p & 7) << 3;
            float zacc = bout[c];
            #pragma unroll 4
            for (int c2 = 0; c2 < 32; ++c2) {
                const int ei = p * 256 + ((c2 * 8) ^ swz);
                half8v vh = *(const half8v*)&ha[ei];
                half8v vl = *(const half8v*)&hb[ei];
                #pragma unroll
                for (int e = 0; e < 8; ++e) {
                    const int k = c2 * 8 + e;
                    float hv = (float)vh[e] + (float)vl[e] * LO_INV;
                    zacc = fmaf(hv, Wout[k * 3 + c], zacc);
                }
            }
            out[pg * 3 + c] = 1.0f / (1.0f + __expf(-zacc));
        }
    }
}

// =====================================================================
// Fallback (fp32, R2 structure) if ws too small for the split weights.
// =====================================================================
__global__ __launch_bounds__(512, 4) void cppn_fused_fp32(
    const float* __restrict__ x, const float* __restrict__ W0,
    const float* __restrict__ b0, const float* __restrict__ Ws,
    const float* __restrict__ bs, const float* __restrict__ Wout,
    const float* __restrict__ bout, float* __restrict__ out, int n)
{
    __shared__ float h[HID][PTS];
    const int tid  = threadIdx.x;
    const int p    = tid & 63;
    const int j0   = __builtin_amdgcn_readfirstlane((tid >> 6) << 5);
    const long pg  = (long)blockIdx.x * PTS + p;
    const bool live = (pg < n);
    {
        float xv[12];
        if (live) {
            const float4* xr = (const float4*)(x + pg * 12);
            float4 a = xr[0], b = xr[1], c = xr[2];
            xv[0]=a.x; xv[1]=a.y; xv[2]=a.z;  xv[3]=a.w;
            xv[4]=b.x; xv[5]=b.y; xv[6]=b.z;  xv[7]=b.w;
            xv[8]=c.x; xv[9]=c.y; xv[10]=c.z; xv[11]=c.w;
        } else {
            #pragma unroll
            for (int k = 0; k < 12; ++k) xv[k] = 0.0f;
        }
        float acc[32];
        #pragma unroll
        for (int q = 0; q < 32; ++q) acc[q] = 0.0f;
        #pragma unroll
        for (int k = 0; k < 12; ++k) {
            const float a = xv[k];
            const float4* wr = (const float4*)(W0 + k * HID + j0);
            #pragma unroll
            for (int q = 0; q < 8; ++q) {
                float4 wv = wr[q];
                acc[4*q+0] = fmaf(a, wv.x, acc[4*q+0]);
                acc[4*q+1] = fmaf(a, wv.y, acc[4*q+1]);
                acc[4*q+2] = fmaf(a, wv.z, acc[4*q+2]);
                acc[4*q+3] = fmaf(a, wv.w, acc[4*q+3]);
            }
        }
        #pragma unroll
        for (int q = 0; q < 8; ++q) {
            float4 b4 = *(const float4*)(b0 + j0 + 4*q);
            h[j0+4*q+0][p] = act<0>(acc[4*q+0] + b4.x);
            h[j0+4*q+1][p] = act<0>(acc[4*q+1] + b4.y);
            h[j0+4*q+2][p] = act<0>(acc[4*q+2] + b4.z);
            h[j0+4*q+3][p] = act<0>(acc[4*q+3] + b4.w);
        }
        __syncthreads();
    }
    auto layerF = [&](const float* __restrict__ W, const float* __restrict__ b, auto mtag) {
        constexpr int M = decltype(mtag)::value;
        float acc[32];
        #pragma unroll
        for (int q = 0; q < 32; ++q) acc[q] = 0.0f;
        #pragma unroll 2
        for (int k = 0; k < HID; ++k) {
            const float a = h[k][p];
            const float4* wr = (const float4*)(W + k * HID + j0);
            #pragma unroll
            for (int q = 0; q < 8; ++q) {
                float4 wv = wr[q];
                acc[4*q+0] = fmaf(a, wv.x, acc[4*q+0]);
                acc[4*q+1] = fmaf(a, wv.y, acc[4*q+1]);
                acc[4*q+2] = fmaf(a, wv.z, acc[4*q+2]);
                acc[4*q+3] = fmaf(a, wv.w, acc[4*q+3]);
            }
        }
        __syncthreads();
        #pragma unroll
        for (int q = 0; q < 8; ++q) {
            float4 b4 = *(const float4*)(b + j0 + 4*q);
            h[j0+4*q+0][p] = act<M>(acc[4*q+0] + b4.x);
            h[j0+4*q+1][p] = act<M>(acc[4*q+1] + b4.y);
            h[j0+4*q+2][p] = act<M>(acc[4*q+2] + b4.z);
            h[j0+4*q+3][p] = act<M>(acc[4*q+3] + b4.w);
        }
        __syncthreads();
    };
    layerF(Ws + 0*65536, bs + 0*256, std::integral_constant<int,1>{});
    layerF(Ws + 1*65536, bs + 1*256, std::integral_constant<int,2>{});
    layerF(Ws + 2*65536, bs + 2*256, std::integral_constant<int,3>{});
    layerF(Ws + 3*65536, bs + 3*256, std::integral_constant<int,0>{});
    layerF(Ws + 4*65536, bs + 4*256, std::integral_constant<int,1>{});
    layerF(Ws + 5*65536, bs + 5*256, std::integral_constant<int,2>{});
    layerF(Ws + 6*65536, bs + 6*256, std::integral_constant<int,3>{});
    layerF(Ws + 7*65536, bs + 7*256, std::integral_constant<int,0>{});
    layerF(Ws + 8*65536, bs + 8*256, std::integral_constant<int,1>{});
    if (tid < 192) {
        const int pp = tid & 63;
        const int c  = tid >> 6;
        const long pgo = (long)blockIdx.x * PTS + pp;
        if (pgo < n) {
            float z = bout[c];
            #pragma unroll 4
            for (int k = 0; k < HID; ++k)
                z = fmaf(h[k][pp], Wout[k * 3 + c], z);
            out[pgo * 3 + c] = 1.0f / (1.0f + __expf(-z));
        }
    }
}

extern "C" void kernel_launch(void* const* d_in, const int* in_sizes, int n_in,
                              void* d_out, int out_size, void* d_ws, size_t ws_size,
                              hipStream_t stream) {
    const float* x    = (const float*)d_in[0];
    const float* W0   = (const float*)d_in[1];
    const float* b0   = (const float*)d_in[2];
    const float* Ws   = (const float*)d_in[3];
    const float* bs   = (const float*)d_in[4];
    const float* Wout = (const float*)d_in[5];
    const float* bout = (const float*)d_in[6];
    float* out = (float*)d_out;

    const int n = in_sizes[0] / 12;
    const int grid = (n + PTS - 1) / PTS;

    const size_t whi_bytes = (size_t)PREP_THREADS * 8 * sizeof(_Float16); // 1,179,648
    const size_t need = 2 * whi_bytes;

    if (ws_size >= need) {
        _Float16* WHI = (_Float16*)d_ws;
        _Float16* WLO = (_Float16*)((char*)d_ws + whi_bytes);
        prep_w<<<(PREP_THREADS + 255) / 256, 256, 0, stream>>>(Ws, WHI, WLO);
        cppn_mfma<<<grid, 512, 0, stream>>>(x, W0, b0, bs, Wout, bout, WHI, WLO, out, n);
    } else {
        cppn_fused_fp32<<<grid, 512, 0, stream>>>(x, W0, b0, Ws, bs, Wout, bout, out, n);
    }
}